// Round 1
// baseline (350.599 us; speedup 1.0000x reference)
//
#include <hip/hip_runtime.h>

namespace {

constexpr int B = 32, G = 50, A = 3, C = 80, H = 52, W = 52;
constexpr int HW = H * W;
constexpr int NCELLS = B * A * H * W;   // 259584
constexpr int ATTRS = 5 + C;            // 85
constexpr float IMG_W = 416.0f, IMG_H = 416.0f;
constexpr float IGNORE_THR = 0.5f;
constexpr int NB = 240;                 // reduce-kernel blocks
constexpr int BT = 256;                 // reduce-kernel threads/block

// scaled anchors = ANCHORS / stride(=8): exact in fp32
__device__ __constant__ float SA0[A] = {1.25f, 2.0f, 4.125f};
__device__ __constant__ float SA1[A] = {1.625f, 3.75f, 2.875f};

// clamped softplus: min(log(1+e^x), 100) == -clip(log(1-sigmoid(x)), -100)
__device__ __forceinline__ float sp(float x) {
    float s = fmaxf(x, 0.0f) + log1pf(expf(-fabsf(x)));
    return fminf(s, 100.0f);
}

// BCE(sigmoid(x), t) with torch-style log clamp at -100
__device__ __forceinline__ float bce_logit(float x, float t) {
    return t * sp(-x) + (1.0f - t) * sp(x);
}

__global__ void build_targets_kernel(const float* __restrict__ tgt,
                                     int* __restrict__ winner,
                                     int* __restrict__ noobj_clear) {
    int idx = blockIdx.x * blockDim.x + threadIdx.x;
    if (idx >= B * G) return;
    int b = idx / G;
    int g = idx - b * G;
    const float* t = tgt + (size_t)idx * 5;
    float gx = t[1] / IMG_W * (float)W;
    float gy = t[2] / IMG_H * (float)H;
    float gw = t[3] / IMG_W * (float)W;
    float gh = t[4] / IMG_H * (float)H;
    int gi = min(max((int)gx, 0), W - 1);
    int gj = min(max((int)gy, 0), H - 1);
    float area_g = (gw + 1.0f) * (gh + 1.0f);
    float best_iou = -1.0f;
    int best = 0;
    float ious[A];
#pragma unroll
    for (int a = 0; a < A; ++a) {
        float iw = fmaxf(fminf(gw, SA0[a]) + 1.0f, 0.0f);
        float ih = fmaxf(fminf(gh, SA1[a]) + 1.0f, 0.0f);
        float inter = iw * ih;
        float area_a = (SA0[a] + 1.0f) * (SA1[a] + 1.0f);
        float iou = inter / (area_g + area_a - inter + 1e-16f);
        ious[a] = iou;
        if (iou > best_iou) { best_iou = iou; best = a; }  // first-max wins (argmax)
    }
#pragma unroll
    for (int a = 0; a < A; ++a)
        if (ious[a] > IGNORE_THR)
            atomicOr(&noobj_clear[((b * A + a) * H + gj) * W + gi], 1);
    // last-g-wins for duplicate scatter indices (JAX .at[].set on CPU applies in order)
    atomicMax(&winner[((b * A + best) * H + gj) * W + gi], g + 1);
}

// acc slots: 0 sx, 1 sy, 2 sw, 3 sh, 4 conf_obj, 5 conf_noobj, 6 cls, 7 npos
__global__ __launch_bounds__(BT) void reduce_kernel(
    const float* __restrict__ in, const float* __restrict__ tgt,
    const int* __restrict__ winner, const int* __restrict__ noobj_clear,
    double* __restrict__ partials) {
    float acc[8] = {0.f, 0.f, 0.f, 0.f, 0.f, 0.f, 0.f, 0.f};

    for (int cell = blockIdx.x * BT + threadIdx.x; cell < NCELLS; cell += NB * BT) {
        int i = cell % W;
        int j = (cell / W) % H;
        int a = (cell / HW) % A;
        int b = cell / (HW * A);
        const float* base = in + (((size_t)b * 255 + a * ATTRS) * H + j) * W + i;
        float x4 = base[4 * HW];
        if (noobj_clear[cell] == 0) acc[5] += sp(x4);  // BCE(conf,0)
        int win = winner[cell];
        if (win > 0) {
            acc[4] += sp(-x4);  // BCE(conf,1)
            const float* t = tgt + ((size_t)b * G + (win - 1)) * 5;
            float gx = t[1] / IMG_W * (float)W;
            float gy = t[2] / IMG_H * (float)H;
            float gw = t[3] / IMG_W * (float)W;
            float gh = t[4] / IMG_H * (float)H;
            int gi = min(max((int)gx, 0), W - 1);  // == i
            int gj = min(max((int)gy, 0), H - 1);  // == j
            float tx = gx - (float)gi;
            float ty = gy - (float)gj;
            float tw = logf(gw / SA0[a] + 1e-16f);
            float th = logf(gh / SA1[a] + 1e-16f);
            float x0 = base[0];
            float x1 = base[HW];
            float x2 = base[2 * HW];
            float x3 = base[3 * HW];
            acc[0] += bce_logit(x0, tx);
            acc[1] += bce_logit(x1, ty);
            float dw = x2 - tw, dh = x3 - th;
            acc[2] += dw * dw;
            acc[3] += dh * dh;
            int cls = min(max((int)t[0], 0), C - 1);
            float scls = 0.0f;
            for (int c = 0; c < C; ++c) {
                float xc = base[(5 + c) * HW];
                scls += (c == cls) ? sp(-xc) : sp(xc);
            }
            acc[6] += scls;
            acc[7] += 1.0f;
        }
    }

    __shared__ double lds[BT / 64][8];
    int wid = threadIdx.x >> 6;
    int lane = threadIdx.x & 63;
#pragma unroll
    for (int q = 0; q < 8; ++q) {
        double v = (double)acc[q];
        for (int o = 32; o > 0; o >>= 1) v += __shfl_down(v, o, 64);
        if (lane == 0) lds[wid][q] = v;
    }
    __syncthreads();
    if (threadIdx.x < 8) {
        double s = 0.0;
#pragma unroll
        for (int w = 0; w < BT / 64; ++w) s += lds[w][threadIdx.x];
        partials[(size_t)blockIdx.x * 8 + threadIdx.x] = s;
    }
}

__global__ void finalize_kernel(const double* __restrict__ partials,
                                float* __restrict__ out) {
    int lane = threadIdx.x;  // 64 threads
    double sums[8];
#pragma unroll
    for (int q = 0; q < 8; ++q) {
        double v = 0.0;
        for (int k = lane; k < NB; k += 64) v += partials[(size_t)k * 8 + q];
        for (int o = 32; o > 0; o >>= 1) v += __shfl_down(v, o, 64);
        sums[q] = v;
    }
    if (lane == 0) {
        const double N = (double)NCELLS;
        double lx = sums[0] / N, ly = sums[1] / N;
        double lw = sums[2] / N, lh = sums[3] / N;
        double lconf = sums[4] / N + 0.5 * sums[5] / N;
        double denom = fmax(sums[7] * (double)C, 1.0);
        double lcls = sums[6] / denom;
        out[0] = (float)(2.5 * (lx + ly) + 2.5 * (lw + lh) + lconf + lcls);
    }
}

}  // namespace

extern "C" void kernel_launch(void* const* d_in, const int* in_sizes, int n_in,
                              void* d_out, int out_size, void* d_ws, size_t ws_size,
                              hipStream_t stream) {
    const float* in = (const float*)d_in[0];   // [32,255,52,52] f32
    const float* tgt = (const float*)d_in[1];  // [32,50,5] f32
    float* out = (float*)d_out;                // scalar f32

    int* winner = (int*)d_ws;
    int* noobj_clear = winner + NCELLS;
    double* partials = (double*)((char*)d_ws + 2 * (size_t)NCELLS * sizeof(int));
    // ws usage: 2*NCELLS*4 B maps + NB*8*8 B partials ≈ 2.09 MB

    hipMemsetAsync(d_ws, 0, 2 * (size_t)NCELLS * sizeof(int), stream);
    build_targets_kernel<<<(B * G + 255) / 256, 256, 0, stream>>>(tgt, winner, noobj_clear);
    reduce_kernel<<<NB, BT, 0, stream>>>(in, tgt, winner, noobj_clear, partials);
    finalize_kernel<<<1, 64, 0, stream>>>(partials, out);
}

// Round 6
// 134.483 us; speedup vs baseline: 2.6070x; 2.6070x over previous
//
#include <hip/hip_runtime.h>

namespace {

constexpr int B = 32, G = 50, A = 3, C = 80, H = 52, W = 52;
constexpr int HW = H * W;               // 2704
constexpr int NCELLS = B * A * HW;      // 259584
constexpr int ATTRS = 5 + C;            // 85
constexpr float IMG_W = 416.0f, IMG_H = 416.0f;
constexpr float IGNORE_THR = 0.5f;

constexpr int NWIN = B * G;                      // 1600 max distinct winner cells
constexpr int NCLR = B * G * A;                  // 4800 max distinct cleared cells
constexpr int NCLR_WAVES = (NCLR + 63) / 64;     // 75
constexpr int SP_WAVES = NWIN + NCLR_WAVES;      // 1675
constexpr int SP_BLOCKS = (SP_WAVES + 3) / 4;    // 419 blocks of 256
constexpr int SP_SLOTS = SP_BLOCKS * 4;          // 1676 wave slots

constexpr int DVEC = NCELLS / 4;                 // 64896 float4 packs
constexpr int DB = (DVEC + 255) / 256;           // 254 dense blocks

// scaled anchors = ANCHORS / stride(=8): exact in fp32
__device__ __constant__ float SA0[A] = {1.25f, 2.0f, 4.125f};
__device__ __constant__ float SA1[A] = {1.625f, 3.75f, 2.875f};

// clamped softplus: min(log(1+e^x), 100) == -clip(log(sigmoid(-x)), -100)
__device__ __forceinline__ float sp(float x) {
    float s = fmaxf(x, 0.0f) + log1pf(expf(-fabsf(x)));
    return fminf(s, 100.0f);
}

// BCE(sigmoid(x), t) with torch-style log clamp at -100
__device__ __forceinline__ float bce_logit(float x, float t) {
    return t * sp(-x) + (1.0f - t) * sp(x);
}

// ---- 1. build targets: winner map + noobj-clear map, compacted lists ----
__global__ void build_targets_kernel(const float* __restrict__ tgt,
                                     int* __restrict__ winner,
                                     int* __restrict__ noobj,
                                     int* __restrict__ counters,  // [0]=win, [1]=clr
                                     int* __restrict__ win_list,
                                     int* __restrict__ clr_list) {
    int idx = blockIdx.x * blockDim.x + threadIdx.x;
    if (idx >= B * G) return;
    int b = idx / G;
    int g = idx - b * G;
    const float* t = tgt + (size_t)idx * 5;
    float gw = t[3] / IMG_W * (float)W;
    float gh = t[4] / IMG_H * (float)H;
    int gi = min(max((int)(t[1] / IMG_W * (float)W), 0), W - 1);
    int gj = min(max((int)(t[2] / IMG_H * (float)H), 0), H - 1);
    float area_g = (gw + 1.0f) * (gh + 1.0f);
    float best_iou = -1.0f;
    int best = 0;
#pragma unroll
    for (int a = 0; a < A; ++a) {
        float iw = fmaxf(fminf(gw, SA0[a]) + 1.0f, 0.0f);
        float ih = fmaxf(fminf(gh, SA1[a]) + 1.0f, 0.0f);
        float inter = iw * ih;
        float area_a = (SA0[a] + 1.0f) * (SA1[a] + 1.0f);
        float iou = inter / (area_g + area_a - inter + 1e-16f);
        if (iou > best_iou) { best_iou = iou; best = a; }  // first-max (argmax)
        if (iou > IGNORE_THR) {
            int cell = ((b * A + a) * H + gj) * W + gi;
            if (atomicOr(&noobj[cell], 1) == 0)
                clr_list[atomicAdd(&counters[1], 1)] = cell;
        }
    }
    int cellw = ((b * A + best) * H + gj) * W + gi;
    // last-g-wins for duplicate scatter indices
    if (atomicMax(&winner[cellw], g + 1) == 0)
        win_list[atomicAdd(&counters[0], 1)] = cellw;
}

// ---- 2. dense: 0.5 * sum sp(conf_logit) over ALL cells, float4-vectorized ----
__global__ __launch_bounds__(256) void dense_kernel(const float* __restrict__ in,
                                                    double* __restrict__ partials) {
    int vid = blockIdx.x * 256 + threadIdx.x;
    float s = 0.0f;
    if (vid < DVEC) {
        int plane = vid / (HW / 4);             // (b,a) pair, 0..95
        int off = (vid - plane * (HW / 4)) * 4;
        int b = plane / A, a = plane - b * A;
        const float4 v = *reinterpret_cast<const float4*>(
            in + ((size_t)(b * 255 + a * ATTRS + 4)) * HW + off);
        s = sp(v.x) + sp(v.y) + sp(v.z) + sp(v.w);
    }
    __shared__ double lds[4];
    double d = (double)s;
    for (int o = 32; o > 0; o >>= 1) d += __shfl_down(d, o, 64);
    int lane = threadIdx.x & 63, wid = threadIdx.x >> 6;
    if (lane == 0) lds[wid] = d;
    __syncthreads();
    if (threadIdx.x == 0)
        partials[blockIdx.x] = 0.5 * (lds[0] + lds[1] + lds[2] + lds[3]);
}

// ---- 3. sparse: one wave per winner cell (85 attrs lane-parallel);
//         trailing waves subtract cleared noobj terms ----
__global__ __launch_bounds__(256) void sparse_kernel(
    const float* __restrict__ in, const float* __restrict__ tgt,
    const int* __restrict__ winner, const int* __restrict__ counters,
    const int* __restrict__ win_list, const int* __restrict__ clr_list,
    double* __restrict__ partials) {
    int w = (blockIdx.x * 256 + threadIdx.x) >> 6;  // global wave id
    int lane = threadIdx.x & 63;
    double main_d = 0.0, cls_d = 0.0;

    if (w < NWIN) {
        if (w < counters[0]) {
            int cell = win_list[w];
            int hw = cell % HW;
            int a = (cell / HW) % A;
            int b = cell / (HW * A);
            int g = winner[cell] - 1;
            const float* t = tgt + ((size_t)b * G + g) * 5;
            float gx = t[1] / IMG_W * (float)W;
            float gy = t[2] / IMG_H * (float)H;
            float gw = t[3] / IMG_W * (float)W;
            float gh = t[4] / IMG_H * (float)H;
            int gi = min(max((int)gx, 0), W - 1);
            int gj = min(max((int)gy, 0), H - 1);
            float tx = gx - (float)gi;
            float ty = gy - (float)gj;
            float tw = logf(gw / SA0[a] + 1e-16f);
            float th = logf(gh / SA1[a] + 1e-16f);
            int cls = min(max((int)t[0], 0), C - 1);
            const float* base = in + ((size_t)(b * 255 + a * ATTRS)) * HW + hw;
            float m = 0.0f, cl = 0.0f;
#pragma unroll
            for (int rep = 0; rep < 2; ++rep) {
                int attr = lane + rep * 64;
                if (attr < ATTRS) {
                    float x = base[(size_t)attr * HW];
                    if (attr == 0) m += 2.5f * bce_logit(x, tx);
                    else if (attr == 1) m += 2.5f * bce_logit(x, ty);
                    else if (attr == 2) { float d = x - tw; m += 2.5f * d * d; }
                    else if (attr == 3) { float d = x - th; m += 2.5f * d * d; }
                    else if (attr == 4) m += sp(-x);          // conf obj term
                    else cl += (attr - 5 == cls) ? sp(-x) : sp(x);
                }
            }
            main_d = (double)m;
            cls_d = (double)cl;
        }
    } else {
        int idx = (w - NWIN) * 64 + lane;
        if (idx < counters[1]) {
            int cell = clr_list[idx];
            int hw = cell % HW;
            int a = (cell / HW) % A;
            int b = cell / (HW * A);
            float x4 = in[((size_t)(b * 255 + a * ATTRS + 4)) * HW + hw];
            main_d = -0.5 * (double)sp(x4);   // remove cleared cell from noobj sum
        }
    }
    for (int o = 32; o > 0; o >>= 1) {
        main_d += __shfl_down(main_d, o, 64);
        cls_d += __shfl_down(cls_d, o, 64);
    }
    if (lane == 0) {
        partials[(size_t)w * 2] = main_d;
        partials[(size_t)w * 2 + 1] = cls_d;
    }
}

// ---- 4. finalize ----
__global__ __launch_bounds__(256) void finalize_kernel(
    const double* __restrict__ dense_partials,
    const double* __restrict__ sparse_partials,
    const int* __restrict__ counters, float* __restrict__ out) {
    double m = 0.0, cl = 0.0;
    for (int k = threadIdx.x; k < DB; k += 256) m += dense_partials[k];
    for (int k = threadIdx.x; k < SP_SLOTS; k += 256) {
        m += sparse_partials[(size_t)k * 2];
        cl += sparse_partials[(size_t)k * 2 + 1];
    }
    __shared__ double lm[4], lc[4];
    for (int o = 32; o > 0; o >>= 1) {
        m += __shfl_down(m, o, 64);
        cl += __shfl_down(cl, o, 64);
    }
    int lane = threadIdx.x & 63, wid = threadIdx.x >> 6;
    if (lane == 0) { lm[wid] = m; lc[wid] = cl; }
    __syncthreads();
    if (threadIdx.x == 0) {
        double mt = lm[0] + lm[1] + lm[2] + lm[3];
        double ct = lc[0] + lc[1] + lc[2] + lc[3];
        double npos = (double)counters[0];
        double denom = fmax(npos * (double)C, 1.0);
        out[0] = (float)(mt / (double)NCELLS + ct / denom);
    }
}

}  // namespace

extern "C" void kernel_launch(void* const* d_in, const int* in_sizes, int n_in,
                              void* d_out, int out_size, void* d_ws, size_t ws_size,
                              hipStream_t stream) {
    const float* in = (const float*)d_in[0];   // [32,255,52,52] f32
    const float* tgt = (const float*)d_in[1];  // [32,50,5] f32
    float* out = (float*)d_out;

    int* winner = (int*)d_ws;
    int* noobj = winner + NCELLS;
    int* counters = noobj + NCELLS;            // 2 ints
    int* win_list = counters + 2;              // NWIN ints
    int* clr_list = win_list + NWIN;           // NCLR ints
    char* p = (char*)(clr_list + NCLR);
    p = (char*)(((uintptr_t)p + 15) & ~(uintptr_t)15);
    double* dense_partials = (double*)p;                 // DB doubles
    double* sparse_partials = dense_partials + DB;       // SP_SLOTS*2 doubles
    // total ws ≈ 2.13 MB

    hipMemsetAsync(d_ws, 0, (2 * (size_t)NCELLS + 2) * sizeof(int), stream);
    build_targets_kernel<<<(B * G + 255) / 256, 256, 0, stream>>>(
        tgt, winner, noobj, counters, win_list, clr_list);
    dense_kernel<<<DB, 256, 0, stream>>>(in, dense_partials);
    sparse_kernel<<<SP_BLOCKS, 256, 0, stream>>>(
        in, tgt, winner, counters, win_list, clr_list, sparse_partials);
    finalize_kernel<<<1, 256, 0, stream>>>(
        dense_partials, sparse_partials, counters, out);
}